// Round 2
// baseline (74.688 us; speedup 1.0000x reference)
//
#include <hip/hip_runtime.h>
#include <hip/hip_bf16.h>

#define BATCH 1024
#define LEN   512
#define NTHREADS 256
#define MARGIN 1.0f

// One block per sample. Ballot-compact pos/neg into LDS, register-tile the
// (pos x neg) hinge sum, block-reduce, and atomicAdd the scaled per-sample
// loss into out[0] (pre-zeroed by hipMemsetAsync in kernel_launch).
__global__ __launch_bounds__(NTHREADS) void per_sample_loss(
    const float* __restrict__ scores,   // [BATCH, LEN]
    const int*   __restrict__ labels,   // [BATCH, LEN], nonzero = positive
    float*       __restrict__ out)      // scalar accumulator
{
    __shared__ __align__(16) float pos[LEN];
    __shared__ __align__(16) float neg[LEN];
    __shared__ int cnt[2];              // [0]=n_pos, [1]=n_neg
    __shared__ float red[NTHREADS / 64];

    const int b    = blockIdx.x;
    const int tid  = threadIdx.x;
    const int lane = tid & 63;
    const int wave = tid >> 6;

    if (tid < 2) cnt[tid] = 0;
    __syncthreads();

    // ---- Compaction: wave ballot + prefix popcount, 2 LDS atomics/wave/iter.
    const unsigned long long lt_mask = (1ull << lane) - 1ull;
    #pragma unroll
    for (int iter = 0; iter < LEN / NTHREADS; ++iter) {
        const int l  = tid + iter * NTHREADS;
        const float s  = scores[b * LEN + l];
        const int   la = labels[b * LEN + l];
        const bool isp = (la != 0);

        const unsigned long long mp = __ballot(isp);
        const int np_wave = __popcll(mp);

        int basep = 0, basen = 0;
        if (lane == 0) {
            basep = atomicAdd(&cnt[0], np_wave);
            basen = atomicAdd(&cnt[1], 64 - np_wave);
        }
        basep = __shfl(basep, 0, 64);
        basen = __shfl(basen, 0, 64);

        if (isp) pos[basep + __popcll(mp  & lt_mask)] = s;
        else     neg[basen + __popcll(~mp & lt_mask)] = s;
    }
    __syncthreads();

    const int n_pos = cnt[0];
    const int n_neg = cnt[1];

    // ---- Sentinel-pad so tiles are branch-free.
    // pos sentinel +1e30 -> q = 1 - 1e30 hugely negative -> contributes 0.
    // neg sentinel -1e30 -> q + n hugely negative -> contributes 0.
    const int npos_pad = (n_pos + 255) & ~255;   // multiple of 256 (<= 512)
    const int nneg_pad = (n_neg + 63)  & ~63;    // multiple of 64  (<= 512)
    for (int i = n_pos + tid; i < npos_pad; i += NTHREADS) pos[i] =  1e30f;
    for (int i = n_neg + tid; i < nneg_pad; i += NTHREADS) neg[i] = -1e30f;
    __syncthreads();

    // ---- Tiled pair loop.
    // Tile = (pos chunk of 256 = 4/lane) x (neg chunk of 64 = 16 float4).
    // Waves round-robin over tiles. Each lane: 1 ds_read_b128 for its 4
    // positives + 16 broadcast ds_read_b128 for the neg chunk -> 256 pairs.
    const int pchunks = npos_pad >> 8;
    const int nchunks = nneg_pad >> 6;
    const int ntiles  = pchunks * nchunks;

    float a0 = 0.f, a1 = 0.f, a2 = 0.f, a3 = 0.f;
    const float4* pos4 = reinterpret_cast<const float4*>(pos);
    const float4* neg4 = reinterpret_cast<const float4*>(neg);

    for (int t = wave; t < ntiles; t += NTHREADS / 64) {
        const int pc = t / nchunks;
        const int nc = t - pc * nchunks;

        const float4 p = pos4[pc * 64 + lane];
        const float q0 = MARGIN - p.x;
        const float q1 = MARGIN - p.y;
        const float q2 = MARGIN - p.z;
        const float q3 = MARGIN - p.w;

        const float4* nb = neg4 + nc * 16;
        #pragma unroll
        for (int j = 0; j < 16; ++j) {
            const float4 n = nb[j];
            a0 += fmaxf(0.f, q0 + n.x) + fmaxf(0.f, q0 + n.y)
                + fmaxf(0.f, q0 + n.z) + fmaxf(0.f, q0 + n.w);
            a1 += fmaxf(0.f, q1 + n.x) + fmaxf(0.f, q1 + n.y)
                + fmaxf(0.f, q1 + n.z) + fmaxf(0.f, q1 + n.w);
            a2 += fmaxf(0.f, q2 + n.x) + fmaxf(0.f, q2 + n.y)
                + fmaxf(0.f, q2 + n.z) + fmaxf(0.f, q2 + n.w);
            a3 += fmaxf(0.f, q3 + n.x) + fmaxf(0.f, q3 + n.y)
                + fmaxf(0.f, q3 + n.z) + fmaxf(0.f, q3 + n.w);
        }
    }

    float acc = (a0 + a1) + (a2 + a3);

    // ---- Wave shuffle reduce, then across the 4 waves, then one atomicAdd.
    #pragma unroll
    for (int off = 32; off > 0; off >>= 1) acc += __shfl_down(acc, off, 64);
    if (lane == 0) red[wave] = acc;
    __syncthreads();

    if (tid == 0) {
        const float s = (red[0] + red[1]) + (red[2] + red[3]);
        const float n_pairs = (float)n_pos * (float)n_neg;
        const float contrib = s / fmaxf(n_pairs, 1.0f) * (1.0f / (float)BATCH);
        atomicAdd(out, contrib);
    }
}

extern "C" void kernel_launch(void* const* d_in, const int* in_sizes, int n_in,
                              void* d_out, int out_size, void* d_ws, size_t ws_size,
                              hipStream_t stream) {
    const float* scores = (const float*)d_in[0];
    const int*   labels = (const int*)d_in[1];
    float*       out    = (float*)d_out;

    hipMemsetAsync(out, 0, sizeof(float), stream);
    per_sample_loss<<<BATCH, NTHREADS, 0, stream>>>(scores, labels, out);
}

// Round 3
// 66.943 us; speedup vs baseline: 1.1157x; 1.1157x over previous
//
#include <hip/hip_runtime.h>
#include <hip/hip_bf16.h>

#define BATCH 1024
#define LEN   512
#define NTHREADS 256
#define MARGIN 1.0f

// Kernel 1: one block per sample. Ballot-compact pos/neg into LDS,
// register-tile the (pos x neg) hinge sum, block-reduce, store ws[b].
// No atomics to global: 1024-way same-address atomicAdd measured +7us (R2).
__global__ __launch_bounds__(NTHREADS) void per_sample_loss(
    const float* __restrict__ scores,   // [BATCH, LEN]
    const int*   __restrict__ labels,   // [BATCH, LEN], nonzero = positive
    float*       __restrict__ ws)       // [BATCH] per-sample loss
{
    __shared__ __align__(16) float pos[LEN];
    __shared__ __align__(16) float neg[LEN];
    __shared__ int cnt[2];              // [0]=n_pos, [1]=n_neg
    __shared__ float red[NTHREADS / 64];

    const int b    = blockIdx.x;
    const int tid  = threadIdx.x;
    const int lane = tid & 63;
    const int wave = tid >> 6;

    if (tid < 2) cnt[tid] = 0;
    __syncthreads();

    // ---- Compaction: wave ballot + prefix popcount, 2 LDS atomics/wave/iter.
    const unsigned long long lt_mask = (1ull << lane) - 1ull;
    #pragma unroll
    for (int iter = 0; iter < LEN / NTHREADS; ++iter) {
        const int l  = tid + iter * NTHREADS;
        const float s  = scores[b * LEN + l];
        const int   la = labels[b * LEN + l];
        const bool isp = (la != 0);

        const unsigned long long mp = __ballot(isp);
        const int np_wave = __popcll(mp);

        int basep = 0, basen = 0;
        if (lane == 0) {
            basep = atomicAdd(&cnt[0], np_wave);
            basen = atomicAdd(&cnt[1], 64 - np_wave);
        }
        basep = __shfl(basep, 0, 64);
        basen = __shfl(basen, 0, 64);

        if (isp) pos[basep + __popcll(mp  & lt_mask)] = s;
        else     neg[basen + __popcll(~mp & lt_mask)] = s;
    }
    __syncthreads();

    const int n_pos = cnt[0];
    const int n_neg = cnt[1];

    // ---- Sentinel-pad so tiles are branch-free.
    // pos sentinel +1e30 -> q = 1 - 1e30 hugely negative -> contributes 0.
    // neg sentinel -1e30 -> q + n hugely negative -> contributes 0.
    const int npos_pad = (n_pos + 255) & ~255;   // multiple of 256 (<= 512)
    const int nneg_pad = (n_neg + 63)  & ~63;    // multiple of 64  (<= 512)
    for (int i = n_pos + tid; i < npos_pad; i += NTHREADS) pos[i] =  1e30f;
    for (int i = n_neg + tid; i < nneg_pad; i += NTHREADS) neg[i] = -1e30f;
    __syncthreads();

    // ---- Tiled pair loop.
    // Tile = (pos chunk of 256 = 4/lane) x (neg chunk of 64 = 16 float4).
    // Waves round-robin over tiles. Each lane: 1 ds_read_b128 for its 4
    // positives + 16 broadcast ds_read_b128 for the neg chunk -> 256 pairs.
    const int pchunks = npos_pad >> 8;
    const int nchunks = nneg_pad >> 6;
    const int ntiles  = pchunks * nchunks;

    float a0 = 0.f, a1 = 0.f, a2 = 0.f, a3 = 0.f;
    const float4* pos4 = reinterpret_cast<const float4*>(pos);
    const float4* neg4 = reinterpret_cast<const float4*>(neg);

    for (int t = wave; t < ntiles; t += NTHREADS / 64) {
        const int pc = t / nchunks;
        const int nc = t - pc * nchunks;

        const float4 p = pos4[pc * 64 + lane];
        const float q0 = MARGIN - p.x;
        const float q1 = MARGIN - p.y;
        const float q2 = MARGIN - p.z;
        const float q3 = MARGIN - p.w;

        const float4* nb = neg4 + nc * 16;
        #pragma unroll
        for (int j = 0; j < 16; ++j) {
            const float4 n = nb[j];
            a0 += fmaxf(0.f, q0 + n.x) + fmaxf(0.f, q0 + n.y)
                + fmaxf(0.f, q0 + n.z) + fmaxf(0.f, q0 + n.w);
            a1 += fmaxf(0.f, q1 + n.x) + fmaxf(0.f, q1 + n.y)
                + fmaxf(0.f, q1 + n.z) + fmaxf(0.f, q1 + n.w);
            a2 += fmaxf(0.f, q2 + n.x) + fmaxf(0.f, q2 + n.y)
                + fmaxf(0.f, q2 + n.z) + fmaxf(0.f, q2 + n.w);
            a3 += fmaxf(0.f, q3 + n.x) + fmaxf(0.f, q3 + n.y)
                + fmaxf(0.f, q3 + n.z) + fmaxf(0.f, q3 + n.w);
        }
    }

    float acc = (a0 + a1) + (a2 + a3);

    // ---- Wave shuffle reduce, then across the 4 waves, single store.
    #pragma unroll
    for (int off = 32; off > 0; off >>= 1) acc += __shfl_down(acc, off, 64);
    if (lane == 0) red[wave] = acc;
    __syncthreads();

    if (tid == 0) {
        const float s = (red[0] + red[1]) + (red[2] + red[3]);
        const float n_pairs = (float)n_pos * (float)n_neg;
        ws[b] = s / fmaxf(n_pairs, 1.0f);
    }
}

// Kernel 2: deterministic reduction of BATCH per-sample losses -> mean.
// One float4 per thread (256 x 4 = 1024).
__global__ __launch_bounds__(NTHREADS) void reduce_batch(
    const float* __restrict__ ws, float* __restrict__ out)
{
    __shared__ float red[NTHREADS / 64];
    const int tid  = threadIdx.x;
    const int lane = tid & 63;
    const int wave = tid >> 6;

    const float4 v = reinterpret_cast<const float4*>(ws)[tid];
    float acc = (v.x + v.y) + (v.z + v.w);

    #pragma unroll
    for (int off = 32; off > 0; off >>= 1) acc += __shfl_down(acc, off, 64);
    if (lane == 0) red[wave] = acc;
    __syncthreads();

    if (tid == 0) {
        out[0] = ((red[0] + red[1]) + (red[2] + red[3])) * (1.0f / (float)BATCH);
    }
}

extern "C" void kernel_launch(void* const* d_in, const int* in_sizes, int n_in,
                              void* d_out, int out_size, void* d_ws, size_t ws_size,
                              hipStream_t stream) {
    const float* scores = (const float*)d_in[0];
    const int*   labels = (const int*)d_in[1];
    float*       out    = (float*)d_out;
    float*       ws     = (float*)d_ws;   // BATCH floats of scratch

    per_sample_loss<<<BATCH, NTHREADS, 0, stream>>>(scores, labels, ws);
    reduce_batch<<<1, NTHREADS, 0, stream>>>(ws, out);
}